// Round 4
// baseline (48.832 us; speedup 1.0000x reference)
//
#include <hip/hip_runtime.h>
#include <math.h>

#define DEV_INLINE __device__ __forceinline__

typedef float v2f __attribute__((ext_vector_type(2)));

constexpr int TRI = 36;      // 8*9/2
#define EPSF 1e-10f

DEV_INLINE constexpr int SI(int i, int j) { return i * (i + 1) / 2 + j; } // i >= j
#define SA(a, i, j) ((i) >= (j) ? (a)[SI((i),(j))] : (a)[SI((j),(i))])

DEV_INLINE v2f sp2(float s) { return (v2f){s, s}; }

DEV_INLINE void waitlds() { asm volatile("s_waitcnt lgkmcnt(0)" ::: "memory"); }

// ---- per-group row staging in LDS (row r: 8 floats at +8r) ----
DEV_INLINE void st_row(float* buf, int r, const v2f x[4]) {
  float4* p = (float4*)buf + 2 * r;
  p[0] = make_float4(x[0].x, x[0].y, x[1].x, x[1].y);
  p[1] = make_float4(x[2].x, x[2].y, x[3].x, x[3].y);
}
DEV_INLINE void ld_row(const float* buf, int r, v2f x[4]) {
  const float4* p = (const float4*)buf + 2 * r;
  float4 a = p[0], b = p[1];
  x[0] = (v2f){a.x, a.y}; x[1] = (v2f){a.z, a.w};
  x[2] = (v2f){b.x, b.y}; x[3] = (v2f){b.z, b.w};
}

// full token density contribution (lower-tri, 36), accumulated with mask/trace
DEV_INLINE void token_accum(const float* __restrict__ emb, int idx, float mask,
                            float acc[TRI], float& msum) {
  float p[TRI];
  const float4* row = reinterpret_cast<const float4*>(emb + (size_t)idx * TRI);
  #pragma unroll
  for (int q = 0; q < 9; ++q) {
    float4 v = row[q];
    p[4 * q + 0] = v.x; p[4 * q + 1] = v.y; p[4 * q + 2] = v.z; p[4 * q + 3] = v.w;
  }
  #pragma unroll
  for (int i = 0; i < 8; ++i) p[SI(i, i)] = fmaxf(p[SI(i, i)], 1e-4f);
  float r[TRI];
  float tr = 0.f;
  #pragma unroll
  for (int i = 0; i < 8; ++i) {
    #pragma unroll
    for (int j = 0; j <= i; ++j) {
      float s = 0.f;
      #pragma unroll
      for (int k = 0; k <= j; ++k) s = fmaf(p[SI(i, k)], p[SI(j, k)], s);
      if (i == j) { s += EPSF; tr += s; }
      r[SI(i, j)] = s;
    }
  }
  float w = mask * __builtin_amdgcn_rcpf(tr + EPSF);
  #pragma unroll
  for (int u = 0; u < TRI; ++u) acc[u] = fmaf(r[u], w, acc[u]);
  msum += mask;
}

__global__ void __launch_bounds__(64, 2)
qcbow_loss_kernel(const int* __restrict__ contexts, const int* __restrict__ targets,
                  const float* __restrict__ emb, float* __restrict__ out,
                  int B, float invB) {
  __shared__ __align__(16) float lds[8 * 132];
  const int tid = threadIdx.x;
  const int g = tid >> 3, i = tid & 7;
  float* bufA = &lds[g * 132];
  float* bufB = bufA + 68;

  int sample = blockIdx.x * 8 + g;
  const float ok = (sample < B) ? 1.f : 0.f;
  if (sample >= B) sample = B - 1;

  // ---- context phase: token-split across the 8 lanes ----
  const int* crow = contexts + (size_t)sample * 10;
  int idx1 = crow[i];
  int off2 = (i < 2) ? (8 + i) : 0;
  int idx2 = crow[off2];
  float m1 = (idx1 != 0) ? 1.f : 0.f;
  float m2 = (i < 2 && idx2 != 0) ? 1.f : 0.f;

  float acc[TRI];
  #pragma unroll
  for (int u = 0; u < TRI; ++u) acc[u] = 0.f;
  float msum = 0.f;
  token_accum(emb, idx1, m1, acc, msum);
  token_accum(emb, idx2, m2, acc, msum);

  // butterfly-reduce R (36) + msum across the 8-lane group
  #pragma unroll
  for (int m = 1; m < 8; m <<= 1) {
    #pragma unroll
    for (int u = 0; u < TRI; ++u) acc[u] += __shfl_xor(acc[u], m, 8);
    msum += __shfl_xor(msum, m, 8);
  }
  float rinv = __builtin_amdgcn_rcpf(msum + EPSF);  // fold into f (Y0 is scale-inv)

  // ---- target: lane i holds column i of T (masked, diag clamped) ----
  int t = targets[sample];
  const float* trow = emb + (size_t)t * TRI;
  float Tc[8];
  #pragma unroll
  for (int k = 0; k < 8; ++k) {
    float v = trow[SI(k, 0) + i];          // element T[k][i] when k>=i
    v = (k == i) ? fmaxf(v, 1e-4f) : v;
    Tc[k] = (k >= i) ? v : 0.f;
  }
  float tq = 0.f;
  #pragma unroll
  for (int k = 0; k < 8; ++k) tq = fmaf(Tc[k], Tc[k], tq);
  #pragma unroll
  for (int m = 1; m < 8; m <<= 1) tq += __shfl_xor(tq, m, 8);
  float trt = tq + 9.f * EPSF;             // tr(TT^T + eps I) + EPS

  // ---- u = R * Tcol_i (R symmetric, full in regs) ----
  v2f u[4];
  #pragma unroll
  for (int m2 = 0; m2 < 4; ++m2) u[m2] = sp2(0.f);
  #pragma unroll
  for (int l = 0; l < 8; ++l) {
    #pragma unroll
    for (int m2 = 0; m2 < 4; ++m2) {
      v2f rl = (v2f){SA(acc, l, 2 * m2), SA(acc, l, 2 * m2 + 1)};
      u[m2] = __builtin_elementwise_fma(sp2(Tc[l]), rl, u[m2]);
    }
  }

  // ---- A row i: A[i][j] = dot(u_i, Tcol_j) via LDS gather of T-columns ----
  {
    float4* p = (float4*)bufA + 2 * i;
    p[0] = make_float4(Tc[0], Tc[1], Tc[2], Tc[3]);
    p[1] = make_float4(Tc[4], Tc[5], Tc[6], Tc[7]);
  }
  waitlds();
  float As[8];
  #pragma unroll
  for (int j = 0; j < 8; ++j) {
    v2f tj[4];
    ld_row(bufA, j, tj);
    v2f d = u[0] * tj[0];
    d = __builtin_elementwise_fma(u[1], tj[1], d);
    d = __builtin_elementwise_fma(u[2], tj[2], d);
    d = __builtin_elementwise_fma(u[3], tj[3], d);
    As[j] = d.x + d.y;
  }

  // unit row e_i, trace of A
  v2f er[4], er15[4];
  #pragma unroll
  for (int m2 = 0; m2 < 4; ++m2) {
    er[m2] = (v2f){(2 * m2 == i) ? 1.f : 0.f, (2 * m2 + 1 == i) ? 1.f : 0.f};
    er15[m2] = er[m2] * sp2(1.5f);
  }
  float diagA = 0.f;
  #pragma unroll
  for (int j = 0; j < 8; ++j) diagA += (j == i) ? As[j] : 0.f;
  float cA = diagA;
  #pragma unroll
  for (int m = 1; m < 8; m <<= 1) cA += __shfl_xor(cA, m, 8);
  float icA = __builtin_amdgcn_rcpf(cA + 1e-30f);

  // ---- NS init: Y0 = A/trA row, peel iter 1 (Z0 = I) ----
  v2f Yr[4], Zr[4];
  #pragma unroll
  for (int m2 = 0; m2 < 4; ++m2) {
    Yr[m2] = (v2f){As[2 * m2], As[2 * m2 + 1]} * sp2(icA);
    Zr[m2] = __builtin_elementwise_fma(Yr[m2], sp2(-0.5f), er15[m2]); // Z1
  }
  st_row(bufB, i, Zr);
  waitlds();
  {
    v2f ya[4];
    #pragma unroll
    for (int m2 = 0; m2 < 4; ++m2) ya[m2] = sp2(0.f);
    #pragma unroll
    for (int k = 0; k < 8; ++k) {
      v2f rk[4];
      ld_row(bufB, k, rk);
      float yk = Yr[k >> 1][k & 1];
      #pragma unroll
      for (int m2 = 0; m2 < 4; ++m2)
        ya[m2] = __builtin_elementwise_fma(sp2(yk), rk[m2], ya[m2]);
    }
    #pragma unroll
    for (int m2 = 0; m2 < 4; ++m2) Yr[m2] = ya[m2];   // Y1
  }

  // ---- NS steps 2..9: shared gathered M rows for Y'=Y*M, Z'=Z*M ----
  #pragma unroll 1
  for (int s = 0; s < 8; ++s) {
    st_row(bufA, i, Yr);
    waitlds();
    v2f macc[4];
    #pragma unroll
    for (int m2 = 0; m2 < 4; ++m2) macc[m2] = sp2(0.f);
    #pragma unroll
    for (int k = 0; k < 8; ++k) {
      v2f rk[4];
      ld_row(bufA, k, rk);
      float zk = Zr[k >> 1][k & 1];
      #pragma unroll
      for (int m2 = 0; m2 < 4; ++m2)
        macc[m2] = __builtin_elementwise_fma(sp2(zk), rk[m2], macc[m2]);
    }
    v2f Mr[4];
    #pragma unroll
    for (int m2 = 0; m2 < 4; ++m2)
      Mr[m2] = __builtin_elementwise_fma(macc[m2], sp2(-0.5f), er15[m2]);
    st_row(bufB, i, Mr);
    waitlds();
    v2f ya[4], za[4];
    #pragma unroll
    for (int m2 = 0; m2 < 4; ++m2) { ya[m2] = sp2(0.f); za[m2] = sp2(0.f); }
    #pragma unroll
    for (int k = 0; k < 8; ++k) {
      v2f rk[4];
      ld_row(bufB, k, rk);
      float yk = Yr[k >> 1][k & 1];
      float zk = Zr[k >> 1][k & 1];
      #pragma unroll
      for (int m2 = 0; m2 < 4; ++m2) {
        ya[m2] = __builtin_elementwise_fma(sp2(yk), rk[m2], ya[m2]);
        za[m2] = __builtin_elementwise_fma(sp2(zk), rk[m2], za[m2]);
      }
    }
    #pragma unroll
    for (int m2 = 0; m2 < 4; ++m2) { Yr[m2] = ya[m2]; Zr[m2] = za[m2]; }
  }

  // ---- final: trY = <Y9, M10>_F ----
  st_row(bufA, i, Yr);
  waitlds();
  v2f macc[4];
  #pragma unroll
  for (int m2 = 0; m2 < 4; ++m2) macc[m2] = sp2(0.f);
  #pragma unroll
  for (int k = 0; k < 8; ++k) {
    v2f rk[4];
    ld_row(bufA, k, rk);
    float zk = Zr[k >> 1][k & 1];
    #pragma unroll
    for (int m2 = 0; m2 < 4; ++m2)
      macc[m2] = __builtin_elementwise_fma(sp2(zk), rk[m2], macc[m2]);
  }
  v2f d = sp2(0.f);
  #pragma unroll
  for (int m2 = 0; m2 < 4; ++m2) {
    v2f Mf = __builtin_elementwise_fma(macc[m2], sp2(-0.5f), er15[m2]);
    d = __builtin_elementwise_fma(Yr[m2], Mf, d);
  }
  float trY = d.x + d.y;
  #pragma unroll
  for (int m = 1; m < 8; m <<= 1) trY += __shfl_xor(trY, m, 8);

  float f = cA * rinv * trY * trY * __builtin_amdgcn_rcpf(trt);
  f = fminf(fmaxf(f, 0.f), 1.f);
  float loss = -logf(fmaxf(f, 1e-8f)) + 0.1f * (1.f - f);
  float val = (i == 0) ? ok * loss * invB : 0.f;
  #pragma unroll
  for (int m = 1; m < 64; m <<= 1) val += __shfl_xor(val, m, 64);
  if (tid == 0) atomicAdd(out, val);
}

extern "C" void kernel_launch(void* const* d_in, const int* in_sizes, int n_in,
                              void* d_out, int out_size, void* d_ws, size_t ws_size,
                              hipStream_t stream) {
  const int* contexts = (const int*)d_in[0];
  const int* targets  = (const int*)d_in[1];
  const float* emb    = (const float*)d_in[2];
  float* out = (float*)d_out;
  const int B = in_sizes[1];

  hipMemsetAsync(out, 0, sizeof(float), stream);
  const int block = 64;                 // 1 wave, 8 samples per block
  const int grid = (B + 7) / 8;
  qcbow_loss_kernel<<<grid, block, 0, stream>>>(contexts, targets, emb, out, B, 1.0f / (float)B);
}